// Round 13
// baseline (199.071 us; speedup 1.0000x reference)
//
#include <hip/hip_runtime.h>
#include <stdint.h>

#define EPSN 1e-12f

typedef float f32x16 __attribute__((ext_vector_type(16)));
typedef float f32x4 __attribute__((ext_vector_type(4)));
typedef __bf16 bf16x8 __attribute__((ext_vector_type(8)));

// ---- bf16 helpers (round-to-nearest-even) ----
__device__ __forceinline__ unsigned short f2bf(float f) {
  union { float f; unsigned int u; } v; v.f = f;
  unsigned int u = v.u + 0x7FFFu + ((v.u >> 16) & 1u);
  return (unsigned short)(u >> 16);
}

// ---- workspace layout (ushort offsets) ----
// Fragment-major packed weights for 32x32x16 MFMA:
//   addr = ((tile*18 + ks)*64 + lane)*8 + j
//   value = W[o = tile*32 + (lane&31)][k = ks*16 + (lane>>5)*8 + j]
#define WQF_OFF 0
#define WKF_OFF 294912
#define WVP_OFF 589824                 // WVt[o][m]  256*64
#define QBG_OFF 606208                 // qbarG: 16384 px * 16 j, fp32 (as ushort off)
#define ATN_OFF 1130496                // attnG: 16384 px * 64 m, bf16

// =====================================================================
// prep: pack weights + WVt + zero qbarG
// blocks [0,512): pack. [512,1536): WVt. [1536,1792): zero qbarG.
// =====================================================================
__global__ __launch_bounds__(256) void prep_kernel(
    const float* __restrict__ wq, const float* __restrict__ bq,
    const float* __restrict__ wk, const float* __restrict__ bk,
    const float* __restrict__ v, const float* __restrict__ wout,
    unsigned short* __restrict__ wsp) {
  int bid = blockIdx.x;
  if (bid < 512) {
    int isK = bid >= 256;
    int ob = (bid & 255) * 4;
    const float* w = isK ? wk : wq;
    const float* bb = isK ? bk : bq;
    unsigned short* dst = wsp + (isK ? WKF_OFF : WQF_OFF);
    for (int i = threadIdx.x; i < 4 * 129; i += 256) {
      int r = i / 129, q = i - r * 129;
      int o = ob + r, k = q * 2;
      float2 w2 = *(const float2*)(w + o * 258 + k);
      int g = o >> 5, col = o & 31;
      int ks = k >> 4, hi = (k >> 3) & 1, j = k & 7;
      uint32_t pk = (uint32_t)f2bf(w2.x) | ((uint32_t)f2bf(w2.y) << 16);
      *(uint32_t*)(dst + (((g * 18 + ks) * 64 + hi * 32 + col) << 3) + j) = pk;
    }
    for (int i = threadIdx.x; i < 4 * 30; i += 256) {
      int r = i / 30, kk = 258 + (i - r * 30);
      int o = ob + r;
      int g = o >> 5, col = o & 31;
      int ks = kk >> 4, hi = (kk >> 3) & 1, j = kk & 7;
      dst[(((g * 18 + ks) * 64 + hi * 32 + col) << 3) + j] =
          (kk == 258) ? f2bf(bb[o]) : (unsigned short)0;
    }
  } else if (bid < 1536) {
    int idx = (bid - 512) * 256 + threadIdx.x;
    int fc = idx & 15, m = (idx >> 4) & 63, o = idx >> 10;
    const f32x4* wo = (const f32x4*)(wout + o * 256 + fc * 16);
    const f32x4* vm = (const f32x4*)(v + m * 256 + fc * 16);
    float s = 0.f;
#pragma unroll
    for (int f = 0; f < 4; ++f) {
      f32x4 a = wo[f], bvv = vm[f];
      s += a[0]*bvv[0] + a[1]*bvv[1] + a[2]*bvv[2] + a[3]*bvv[3];
    }
    s += __shfl_xor(s, 1, 64);
    s += __shfl_xor(s, 2, 64);
    s += __shfl_xor(s, 4, 64);
    s += __shfl_xor(s, 8, 64);
    if (fc == 0) wsp[WVP_OFF + o * 64 + m] = f2bf(s);
  } else {
    int idx = (bid - 1536) * 256 + threadIdx.x;   // [0, 65536)
    ((f32x4*)(wsp + QBG_OFF))[idx] = (f32x4)0.f;  // 1 MB zeroed
  }
}

// =====================================================================
// shared staging: xpF[((ks*2+q2)*128 + pxl)*8 + jj] = bf16 of channel
// c = ks*16+q2*8+jj, pixel pxl  — fragment-sequential, conflict-free b128.
// =====================================================================
__device__ __forceinline__ void stage128(const float* __restrict__ x,
                                         const float* __restrict__ pos,
                                         unsigned short* xpF,
                                         int b, int s0, int tid) {
  uint32_t* xp32 = (uint32_t*)xpF;
  for (int i = tid; i < 128 * 144; i += 1024) {
    int p = i & 127, dcol = i >> 7;
    int c0 = dcol * 2;
    float v0, v1;
    if (c0 < 256) {
      v0 = x[(b * 256 + c0) * 4096 + s0 + p];
      v1 = x[(b * 256 + c0 + 1) * 4096 + s0 + p];
    } else if (c0 == 256) {
      v0 = pos[s0 + p];
      v1 = pos[4096 + s0 + p];
    } else {
      v0 = (c0 == 258) ? 1.0f : 0.0f;   // bias channel at 258
      v1 = 0.0f;
    }
    xp32[(dcol >> 2) * 512 + p * 4 + (dcol & 3)] =
        (uint32_t)f2bf(v0) | ((uint32_t)f2bf(v1) << 16);
  }
}

// =====================================================================
// K1: q projection, 256 rows x 128 px per block.
// grid = 128 pg x 4 og. 16 waves: wave = 2 o-tiles x 1 px-tile.
// Norm per m + qbar partial -> LDS -> global fp32 atomics.
// =====================================================================
__global__ __launch_bounds__(1024, 4) void qproj_kernel(
    const float* __restrict__ x, const float* __restrict__ pos,
    const unsigned short* __restrict__ wsp, float* __restrict__ qbarG) {
  __shared__ __align__(16) unsigned short xpF[18 * 2 * 128 * 8];  // 73728 B
  __shared__ float qbp[16 * 128];                                 // 8192 B

  const int tid = threadIdx.x;
  const int lane = tid & 63;
  const int wid = __builtin_amdgcn_readfirstlane(tid >> 6);
  const int px = lane & 31, q2 = lane >> 5;
  const int pg = blockIdx.x & 127, og = blockIdx.x >> 7;
  const int PX0 = pg * 128;
  const int b = PX0 >> 12, s0 = PX0 & 4095;

  stage128(x, pos, xpF, b, s0, tid);
  for (int i = tid; i < 16 * 128; i += 1024) qbp[i] = 0.f;
  __syncthreads();

  const int wot = (wid >> 2) * 2, wp = wid & 3;
  const unsigned short* a0p = wsp + WQF_OFF + ((og * 8 + wot) * 18 * 64 + lane) * 8;
  const unsigned short* a1p = a0p + 18 * 512;
  const unsigned short* bvp = &xpF[(q2 * 128 + wp * 32 + px) * 8];

  f32x16 acc0 = (f32x16)0.f, acc1 = (f32x16)0.f;
#pragma unroll
  for (int ks = 0; ks < 18; ++ks) {
    bf16x8 bv = *(const bf16x8*)(bvp + ks * 2048);
    bf16x8 a0 = *(const bf16x8*)(a0p + ks * 512);
    bf16x8 a1 = *(const bf16x8*)(a1p + ks * 512);
    acc0 = __builtin_amdgcn_mfma_f32_32x32x16_bf16(a0, bv, acc0, 0, 0, 0);
    acc1 = __builtin_amdgcn_mfma_f32_32x32x16_bf16(a1, bv, acc1, 0, 0, 0);
  }

  float qsum[8];
#pragma unroll
  for (int r = 0; r < 8; ++r) qsum[r] = 0.f;
#pragma unroll
  for (int t = 0; t < 2; ++t) {
    const f32x16 a = t ? acc1 : acc0;
    float s20 = 0.f, s21 = 0.f;
#pragma unroll
    for (int r = 0; r < 8; ++r) {
      s20 = fmaf(a[r], a[r], s20);
      s21 = fmaf(a[r + 8], a[r + 8], s21);
    }
    s20 += __shfl_xor(s20, 32, 64);
    s21 += __shfl_xor(s21, 32, 64);
    float i0 = 1.0f / fmaxf(sqrtf(s20), EPSN);
    float i1 = 1.0f / fmaxf(sqrtf(s21), EPSN);
#pragma unroll
    for (int r = 0; r < 8; ++r) qsum[r] += a[r] * i0 + a[r + 8] * i1;
  }
#pragma unroll
  for (int r = 0; r < 8; ++r) {
    int j = (r & 3) + ((r >> 2) << 3) + (q2 << 2);
    atomicAdd(&qbp[j * 128 + wp * 32 + px], qsum[r] * (1.0f / 64.0f));
  }
  __syncthreads();
  for (int i = tid; i < 2048; i += 1024) {
    int j = i >> 7, p = i & 127;
    atomicAdd(qbarG + (PX0 + p) * 16 + j, qbp[i]);
  }
}

// =====================================================================
// K2: k projection (same tiling) + attn = qbar . kn -> attnG (bf16)
// =====================================================================
__global__ __launch_bounds__(1024, 4) void kattn_kernel(
    const float* __restrict__ x, const float* __restrict__ pos,
    const unsigned short* __restrict__ wsp, const float* __restrict__ qbarG,
    unsigned short* __restrict__ attnG) {
  __shared__ __align__(16) unsigned short xpF[18 * 2 * 128 * 8];  // 73728 B

  const int tid = threadIdx.x;
  const int lane = tid & 63;
  const int wid = __builtin_amdgcn_readfirstlane(tid >> 6);
  const int px = lane & 31, q2 = lane >> 5;
  const int pg = blockIdx.x & 127, og = blockIdx.x >> 7;
  const int PX0 = pg * 128;
  const int b = PX0 >> 12, s0 = PX0 & 4095;

  stage128(x, pos, xpF, b, s0, tid);
  __syncthreads();

  const int wot = (wid >> 2) * 2, wp = wid & 3;
  const unsigned short* a0p = wsp + WKF_OFF + ((og * 8 + wot) * 18 * 64 + lane) * 8;
  const unsigned short* a1p = a0p + 18 * 512;
  const unsigned short* bvp = &xpF[(q2 * 128 + wp * 32 + px) * 8];

  f32x16 acc0 = (f32x16)0.f, acc1 = (f32x16)0.f;
#pragma unroll
  for (int ks = 0; ks < 18; ++ks) {
    bf16x8 bv = *(const bf16x8*)(bvp + ks * 2048);
    bf16x8 a0 = *(const bf16x8*)(a0p + ks * 512);
    bf16x8 a1 = *(const bf16x8*)(a1p + ks * 512);
    acc0 = __builtin_amdgcn_mfma_f32_32x32x16_bf16(a0, bv, acc0, 0, 0, 0);
    acc1 = __builtin_amdgcn_mfma_f32_32x32x16_bf16(a1, bv, acc1, 0, 0, 0);
  }

  const int pxg = PX0 + wp * 32 + px;
  float qb[8];
#pragma unroll
  for (int r = 0; r < 8; ++r) {
    int j = (r & 3) + ((r >> 2) << 3) + (q2 << 2);
    qb[r] = qbarG[pxg * 16 + j];
  }
#pragma unroll
  for (int t = 0; t < 2; ++t) {
    const f32x16 a = t ? acc1 : acc0;
    float s20 = 0.f, s21 = 0.f, sp0 = 0.f, sp1 = 0.f;
#pragma unroll
    for (int r = 0; r < 8; ++r) {
      s20 = fmaf(a[r], a[r], s20);         sp0 = fmaf(qb[r], a[r], sp0);
      s21 = fmaf(a[r + 8], a[r + 8], s21); sp1 = fmaf(qb[r], a[r + 8], sp1);
    }
    s20 += __shfl_xor(s20, 32, 64);
    s21 += __shfl_xor(s21, 32, 64);
    sp0 += __shfl_xor(sp0, 32, 64);
    sp1 += __shfl_xor(sp1, 32, 64);
    if (q2 == 0) {
      int m0 = og * 16 + (wot + t) * 2;
      attnG[pxg * 64 + m0]     = f2bf(sp0 / fmaxf(sqrtf(s20), EPSN));
      attnG[pxg * 64 + m0 + 1] = f2bf(sp1 / fmaxf(sqrtf(s21), EPSN));
    }
  }
}

// =====================================================================
// K3: epilogue — out = x + bout + WVt @ attn.  256 blocks x 64 px.
// Wave = 1 of 16 tiles (8 o-tiles x 2 px-tiles), K=64 (4 MFMA).
// =====================================================================
__global__ __launch_bounds__(1024, 8) void epi_kernel(
    const float* __restrict__ x, const unsigned short* __restrict__ wsp,
    const unsigned short* __restrict__ attnG, const float* __restrict__ bout,
    float* __restrict__ out) {
  __shared__ float boutL[256];
  const int tid = threadIdx.x;
  const int lane = tid & 63;
  const int wid = __builtin_amdgcn_readfirstlane(tid >> 6);
  const int px = lane & 31, q2 = lane >> 5;
  const int P0 = blockIdx.x * 64;
  const int b = P0 >> 12, s0 = P0 & 4095;

  if (tid < 256) boutL[tid] = bout[tid];
  __syncthreads();

  const int otile = wid >> 1, pxt = wid & 1;
  f32x16 e = (f32x16)0.f;
  const unsigned short* wv = wsp + WVP_OFF + (otile * 32 + px) * 64 + q2 * 8;
  const unsigned short* ab = attnG + (P0 + pxt * 32 + px) * 64 + q2 * 8;
#pragma unroll
  for (int ks = 0; ks < 4; ++ks) {
    bf16x8 av = *(const bf16x8*)(wv + ks * 16);
    bf16x8 bv = *(const bf16x8*)(ab + ks * 16);
    e = __builtin_amdgcn_mfma_f32_32x32x16_bf16(av, bv, e, 0, 0, 0);
  }
#pragma unroll
  for (int r = 0; r < 16; ++r) {
    const int o = otile * 32 + (r & 3) + (((r >> 2) & 1) << 3) + (q2 << 2) + ((r >> 3) << 4);
    const int gi = (b * 256 + o) * 4096 + s0 + pxt * 32 + px;
    out[gi] = x[gi] + boutL[o] + e[r];
  }
}

// =====================================================================
extern "C" void kernel_launch(void* const* d_in, const int* in_sizes, int n_in,
                              void* d_out, int out_size, void* d_ws, size_t ws_size,
                              hipStream_t stream) {
  const float* x    = (const float*)d_in[0];
  const float* pos  = (const float*)d_in[1];
  const float* wq   = (const float*)d_in[2];
  const float* bq   = (const float*)d_in[3];
  const float* wk   = (const float*)d_in[4];
  const float* bk   = (const float*)d_in[5];
  const float* v    = (const float*)d_in[6];
  const float* wout = (const float*)d_in[7];
  const float* bout = (const float*)d_in[8];
  float* out = (float*)d_out;
  unsigned short* wsp = (unsigned short*)d_ws;
  float* qbarG = (float*)(wsp + QBG_OFF);
  unsigned short* attnG = wsp + ATN_OFF;

  hipLaunchKernelGGL(prep_kernel, dim3(1792), dim3(256), 0, stream,
                     wq, bq, wk, bk, v, wout, wsp);
  hipLaunchKernelGGL(qproj_kernel, dim3(512), dim3(1024), 0, stream,
                     x, pos, wsp, qbarG);
  hipLaunchKernelGGL(kattn_kernel, dim3(512), dim3(1024), 0, stream,
                     x, pos, wsp, qbarG, attnG);
  hipLaunchKernelGGL(epi_kernel, dim3(256), dim3(1024), 0, stream,
                     x, wsp, attnG, bout, out);
}

// Round 14
// 155.535 us; speedup vs baseline: 1.2799x; 1.2799x over previous
//
#include <hip/hip_runtime.h>
#include <stdint.h>

#define EPSN 1e-12f

typedef float f32x16 __attribute__((ext_vector_type(16)));
typedef float f32x4 __attribute__((ext_vector_type(4)));
typedef __bf16 bf16x8 __attribute__((ext_vector_type(8)));

// ---- bf16 helpers (round-to-nearest-even) ----
__device__ __forceinline__ unsigned short f2bf(float f) {
  union { float f; unsigned int u; } v; v.f = f;
  unsigned int u = v.u + 0x7FFFu + ((v.u >> 16) & 1u);
  return (unsigned short)(u >> 16);
}
__device__ __forceinline__ float bf2f(unsigned short h) {
  union { unsigned int u; float f; } v; v.u = ((unsigned int)h) << 16;
  return v.f;
}

// ---- workspace layout (ushort offsets) ----
// Fragment-major packed weights for 32x32x16 MFMA:
//   addr = ((tile*18 + ks)*64 + lane)*8 + j
//   value = W[o = tile*32 + (lane&31)][k = ks*16 + (lane>>5)*8 + j]
#define WQF_OFF 0
#define WKF_OFF 294912
#define WVP_OFF 589824    // WVt[o][m]  256*64 shorts
#define QBP_OFF 606208    // qbarP: [pg*4+og][16 j][128 px] bf16 = 1M shorts
#define ATN_OFF 1654784   // attnG: 16384 px * 64 m, bf16 = 1M shorts

// =====================================================================
// prep: pack weights + WVt  (R14: qbar zeroing dropped — plain stores now)
// =====================================================================
__global__ __launch_bounds__(256) void prep_kernel(
    const float* __restrict__ wq, const float* __restrict__ bq,
    const float* __restrict__ wk, const float* __restrict__ bk,
    const float* __restrict__ v, const float* __restrict__ wout,
    unsigned short* __restrict__ wsp) {
  int bid = blockIdx.x;
  if (bid < 512) {
    int isK = bid >= 256;
    int ob = (bid & 255) * 4;
    const float* w = isK ? wk : wq;
    const float* bb = isK ? bk : bq;
    unsigned short* dst = wsp + (isK ? WKF_OFF : WQF_OFF);
    for (int i = threadIdx.x; i < 4 * 129; i += 256) {
      int r = i / 129, q = i - r * 129;
      int o = ob + r, k = q * 2;
      float2 w2 = *(const float2*)(w + o * 258 + k);
      int g = o >> 5, col = o & 31;
      int ks = k >> 4, hi = (k >> 3) & 1, j = k & 7;
      uint32_t pk = (uint32_t)f2bf(w2.x) | ((uint32_t)f2bf(w2.y) << 16);
      *(uint32_t*)(dst + (((g * 18 + ks) * 64 + hi * 32 + col) << 3) + j) = pk;
    }
    for (int i = threadIdx.x; i < 4 * 30; i += 256) {
      int r = i / 30, kk = 258 + (i - r * 30);
      int o = ob + r;
      int g = o >> 5, col = o & 31;
      int ks = kk >> 4, hi = (kk >> 3) & 1, j = kk & 7;
      dst[(((g * 18 + ks) * 64 + hi * 32 + col) << 3) + j] =
          (kk == 258) ? f2bf(bb[o]) : (unsigned short)0;
    }
  } else {
    int idx = (bid - 512) * 256 + threadIdx.x;
    int fc = idx & 15, m = (idx >> 4) & 63, o = idx >> 10;
    const f32x4* wo = (const f32x4*)(wout + o * 256 + fc * 16);
    const f32x4* vm = (const f32x4*)(v + m * 256 + fc * 16);
    float s = 0.f;
#pragma unroll
    for (int f = 0; f < 4; ++f) {
      f32x4 a = wo[f], bvv = vm[f];
      s += a[0]*bvv[0] + a[1]*bvv[1] + a[2]*bvv[2] + a[3]*bvv[3];
    }
    s += __shfl_xor(s, 1, 64);
    s += __shfl_xor(s, 2, 64);
    s += __shfl_xor(s, 4, 64);
    s += __shfl_xor(s, 8, 64);
    if (fc == 0) wsp[WVP_OFF + o * 64 + m] = f2bf(s);
  }
}

// =====================================================================
// shared staging: xpF[((ks*2+q2)*128 + pxl)*8 + jj] = bf16 of channel
// c = ks*16+q2*8+jj, pixel pxl — fragment-sequential layout.
// =====================================================================
__device__ __forceinline__ void stage128(const float* __restrict__ x,
                                         const float* __restrict__ pos,
                                         unsigned short* xpF,
                                         int b, int s0, int tid) {
  uint32_t* xp32 = (uint32_t*)xpF;
  for (int i = tid; i < 128 * 144; i += 1024) {
    int p = i & 127, dcol = i >> 7;
    int c0 = dcol * 2;
    float v0, v1;
    if (c0 < 256) {
      v0 = x[(b * 256 + c0) * 4096 + s0 + p];
      v1 = x[(b * 256 + c0 + 1) * 4096 + s0 + p];
    } else if (c0 == 256) {
      v0 = pos[s0 + p];
      v1 = pos[4096 + s0 + p];
    } else {
      v0 = (c0 == 258) ? 1.0f : 0.0f;   // bias channel at 258
      v1 = 0.0f;
    }
    xp32[(dcol >> 2) * 512 + p * 4 + (dcol & 3)] =
        (uint32_t)f2bf(v0) | ((uint32_t)f2bf(v1) << 16);
  }
}

// =====================================================================
// K1: q projection, 256 rows x 128 px per block; grid = 128 pg x 4 og.
// R14: qbar partial -> LDS (4-way atomics) -> PLAIN coalesced bf16 store
// to this block's own qbarP slice. No device-scope atomics.
// =====================================================================
__global__ __launch_bounds__(1024, 4) void qproj_kernel(
    const float* __restrict__ x, const float* __restrict__ pos,
    const unsigned short* __restrict__ wsp, unsigned short* __restrict__ qbarP) {
  __shared__ __align__(16) unsigned short xpF[18 * 2 * 128 * 8];  // 73728 B
  __shared__ float qbp[16 * 128];                                 // 8192 B

  const int tid = threadIdx.x;
  const int lane = tid & 63;
  const int wid = __builtin_amdgcn_readfirstlane(tid >> 6);
  const int px = lane & 31, q2 = lane >> 5;
  const int pg = blockIdx.x & 127, og = blockIdx.x >> 7;
  const int PX0 = pg * 128;
  const int b = PX0 >> 12, s0 = PX0 & 4095;

  stage128(x, pos, xpF, b, s0, tid);
  for (int i = tid; i < 16 * 128; i += 1024) qbp[i] = 0.f;
  __syncthreads();

  const int wot = (wid >> 2) * 2, wp = wid & 3;
  const unsigned short* a0p = wsp + WQF_OFF + ((og * 8 + wot) * 18 * 64 + lane) * 8;
  const unsigned short* a1p = a0p + 18 * 512;
  const unsigned short* bvp = &xpF[(q2 * 128 + wp * 32 + px) * 8];

  f32x16 acc0 = (f32x16)0.f, acc1 = (f32x16)0.f;
#pragma unroll
  for (int ks = 0; ks < 18; ++ks) {
    bf16x8 bv = *(const bf16x8*)(bvp + ks * 2048);
    bf16x8 a0 = *(const bf16x8*)(a0p + ks * 512);
    bf16x8 a1 = *(const bf16x8*)(a1p + ks * 512);
    acc0 = __builtin_amdgcn_mfma_f32_32x32x16_bf16(a0, bv, acc0, 0, 0, 0);
    acc1 = __builtin_amdgcn_mfma_f32_32x32x16_bf16(a1, bv, acc1, 0, 0, 0);
  }

  float qsum[8];
#pragma unroll
  for (int r = 0; r < 8; ++r) qsum[r] = 0.f;
#pragma unroll
  for (int t = 0; t < 2; ++t) {
    const f32x16 a = t ? acc1 : acc0;
    float s20 = 0.f, s21 = 0.f;
#pragma unroll
    for (int r = 0; r < 8; ++r) {
      s20 = fmaf(a[r], a[r], s20);
      s21 = fmaf(a[r + 8], a[r + 8], s21);
    }
    s20 += __shfl_xor(s20, 32, 64);
    s21 += __shfl_xor(s21, 32, 64);
    float i0 = 1.0f / fmaxf(sqrtf(s20), EPSN);
    float i1 = 1.0f / fmaxf(sqrtf(s21), EPSN);
#pragma unroll
    for (int r = 0; r < 8; ++r) qsum[r] += a[r] * i0 + a[r + 8] * i1;
  }
#pragma unroll
  for (int r = 0; r < 8; ++r) {
    int j = (r & 3) + ((r >> 2) << 3) + (q2 << 2);
    atomicAdd(&qbp[j * 128 + wp * 32 + px], qsum[r] * (1.0f / 64.0f));
  }
  __syncthreads();
  // plain coalesced partial store: this block owns slice (pg*4+og)
  unsigned short* dst = qbarP + (pg * 4 + og) * 2048;
  for (int i = tid; i < 2048; i += 1024) dst[i] = f2bf(qbp[i]);
}

// =====================================================================
// K2: k projection (same tiling) + qbar 4-slice reduction + attn -> attnG
// =====================================================================
__global__ __launch_bounds__(1024, 4) void kattn_kernel(
    const float* __restrict__ x, const float* __restrict__ pos,
    const unsigned short* __restrict__ wsp,
    const unsigned short* __restrict__ qbarP,
    unsigned short* __restrict__ attnG) {
  __shared__ __align__(16) unsigned short xpF[18 * 2 * 128 * 8];  // 73728 B

  const int tid = threadIdx.x;
  const int lane = tid & 63;
  const int wid = __builtin_amdgcn_readfirstlane(tid >> 6);
  const int px = lane & 31, q2 = lane >> 5;
  const int pg = blockIdx.x & 127, og = blockIdx.x >> 7;
  const int PX0 = pg * 128;
  const int b = PX0 >> 12, s0 = PX0 & 4095;

  stage128(x, pos, xpF, b, s0, tid);
  __syncthreads();

  const int wot = (wid >> 2) * 2, wp = wid & 3;
  const unsigned short* a0p = wsp + WKF_OFF + ((og * 8 + wot) * 18 * 64 + lane) * 8;
  const unsigned short* a1p = a0p + 18 * 512;
  const unsigned short* bvp = &xpF[(q2 * 128 + wp * 32 + px) * 8];

  f32x16 acc0 = (f32x16)0.f, acc1 = (f32x16)0.f;
#pragma unroll
  for (int ks = 0; ks < 18; ++ks) {
    bf16x8 bv = *(const bf16x8*)(bvp + ks * 2048);
    bf16x8 a0 = *(const bf16x8*)(a0p + ks * 512);
    bf16x8 a1 = *(const bf16x8*)(a1p + ks * 512);
    acc0 = __builtin_amdgcn_mfma_f32_32x32x16_bf16(a0, bv, acc0, 0, 0, 0);
    acc1 = __builtin_amdgcn_mfma_f32_32x32x16_bf16(a1, bv, acc1, 0, 0, 0);
  }

  const int pxl = wp * 32 + px;        // [0,128) within the pixel group
  const int pxg = PX0 + pxl;
  float qb[8];
#pragma unroll
  for (int r = 0; r < 8; ++r) {
    int j = (r & 3) + ((r >> 2) << 3) + (q2 << 2);
    const unsigned short* qp = qbarP + pg * 4 * 2048 + j * 128 + pxl;
    qb[r] = bf2f(qp[0]) + bf2f(qp[2048]) + bf2f(qp[4096]) + bf2f(qp[6144]);
  }
#pragma unroll
  for (int t = 0; t < 2; ++t) {
    const f32x16 a = t ? acc1 : acc0;
    float s20 = 0.f, s21 = 0.f, sp0 = 0.f, sp1 = 0.f;
#pragma unroll
    for (int r = 0; r < 8; ++r) {
      s20 = fmaf(a[r], a[r], s20);         sp0 = fmaf(qb[r], a[r], sp0);
      s21 = fmaf(a[r + 8], a[r + 8], s21); sp1 = fmaf(qb[r], a[r + 8], sp1);
    }
    s20 += __shfl_xor(s20, 32, 64);
    s21 += __shfl_xor(s21, 32, 64);
    sp0 += __shfl_xor(sp0, 32, 64);
    sp1 += __shfl_xor(sp1, 32, 64);
    if (q2 == 0) {
      int m0 = og * 16 + (wot + t) * 2;
      attnG[pxg * 64 + m0]     = f2bf(sp0 / fmaxf(sqrtf(s20), EPSN));
      attnG[pxg * 64 + m0 + 1] = f2bf(sp1 / fmaxf(sqrtf(s21), EPSN));
    }
  }
}

// =====================================================================
// K3: epilogue — out = x + bout + WVt @ attn.  256 blocks x 64 px.
// =====================================================================
__global__ __launch_bounds__(1024, 8) void epi_kernel(
    const float* __restrict__ x, const unsigned short* __restrict__ wsp,
    const unsigned short* __restrict__ attnG, const float* __restrict__ bout,
    float* __restrict__ out) {
  __shared__ float boutL[256];
  const int tid = threadIdx.x;
  const int lane = tid & 63;
  const int wid = __builtin_amdgcn_readfirstlane(tid >> 6);
  const int px = lane & 31, q2 = lane >> 5;
  const int P0 = blockIdx.x * 64;
  const int b = P0 >> 12, s0 = P0 & 4095;

  if (tid < 256) boutL[tid] = bout[tid];
  __syncthreads();

  const int otile = wid >> 1, pxt = wid & 1;
  f32x16 e = (f32x16)0.f;
  const unsigned short* wv = wsp + WVP_OFF + (otile * 32 + px) * 64 + q2 * 8;
  const unsigned short* ab = attnG + (P0 + pxt * 32 + px) * 64 + q2 * 8;
#pragma unroll
  for (int ks = 0; ks < 4; ++ks) {
    bf16x8 av = *(const bf16x8*)(wv + ks * 16);
    bf16x8 bv = *(const bf16x8*)(ab + ks * 16);
    e = __builtin_amdgcn_mfma_f32_32x32x16_bf16(av, bv, e, 0, 0, 0);
  }
#pragma unroll
  for (int r = 0; r < 16; ++r) {
    const int o = otile * 32 + (r & 3) + (((r >> 2) & 1) << 3) + (q2 << 2) + ((r >> 3) << 4);
    const int gi = (b * 256 + o) * 4096 + s0 + pxt * 32 + px;
    out[gi] = x[gi] + boutL[o] + e[r];
  }
}

// =====================================================================
extern "C" void kernel_launch(void* const* d_in, const int* in_sizes, int n_in,
                              void* d_out, int out_size, void* d_ws, size_t ws_size,
                              hipStream_t stream) {
  const float* x    = (const float*)d_in[0];
  const float* pos  = (const float*)d_in[1];
  const float* wq   = (const float*)d_in[2];
  const float* bq   = (const float*)d_in[3];
  const float* wk   = (const float*)d_in[4];
  const float* bk   = (const float*)d_in[5];
  const float* v    = (const float*)d_in[6];
  const float* wout = (const float*)d_in[7];
  const float* bout = (const float*)d_in[8];
  float* out = (float*)d_out;
  unsigned short* wsp = (unsigned short*)d_ws;
  unsigned short* qbarP = wsp + QBP_OFF;
  unsigned short* attnG = wsp + ATN_OFF;

  hipLaunchKernelGGL(prep_kernel, dim3(1536), dim3(256), 0, stream,
                     wq, bq, wk, bk, v, wout, wsp);
  hipLaunchKernelGGL(qproj_kernel, dim3(512), dim3(1024), 0, stream,
                     x, pos, wsp, qbarP);
  hipLaunchKernelGGL(kattn_kernel, dim3(512), dim3(1024), 0, stream,
                     x, pos, wsp, qbarP, attnG);
  hipLaunchKernelGGL(epi_kernel, dim3(256), dim3(1024), 0, stream,
                     x, wsp, attnG, bout, out);
}